// Round 2
// baseline (72.588 us; speedup 1.0000x reference)
//
#include <hip/hip_runtime.h>
#include <hip/hip_bf16.h>

#define T_SEQ 1024
#define D_MODEL 256

typedef __attribute__((ext_vector_type(8))) short s16x8;
typedef __attribute__((ext_vector_type(4))) float f32x4v;

__device__ __forceinline__ unsigned short f2bf(float x) {
    union { float f; unsigned int u; } v; v.f = x;
    unsigned int r = v.u + 0x7FFFu + ((v.u >> 16) & 1u);
    return (unsigned short)(r >> 16);
}

// 8 consecutive f32 -> bf16x8 via packed cvt (compiler emits v_cvt_pk_bf16_f32)
__device__ __forceinline__ s16x8 pack8(float4 a, float4 b) {
    union { s16x8 v; unsigned int u[4]; } r;
    union { __hip_bfloat162 h; unsigned int u; } t;
    t.h = __float22bfloat162_rn(make_float2(a.x, a.y)); r.u[0] = t.u;
    t.h = __float22bfloat162_rn(make_float2(a.z, a.w)); r.u[1] = t.u;
    t.h = __float22bfloat162_rn(make_float2(b.x, b.y)); r.u[2] = t.u;
    t.h = __float22bfloat162_rn(make_float2(b.z, b.w)); r.u[3] = t.u;
    return r.v;
}

#define SMEM_BYTES 95488

// one block per (b, h, 64-query tile); 512 threads = 8 waves
__global__ __launch_bounds__(512) void attn_fused(
    const float* __restrict__ x,
    const float* __restrict__ Wq, const float* __restrict__ bq,
    const float* __restrict__ Wk, const float* __restrict__ bk,
    const float* __restrict__ Wv, const float* __restrict__ bv,
    const float* __restrict__ shift_logits, const float* __restrict__ alibi_slope,
    unsigned short* __restrict__ ctxb)
{
    extern __shared__ char smem[];
    float (*S)[168]            = (float(*)[168])(smem);                       // 64*168*4 = 43008
    unsigned short (*v0T)[168] = (unsigned short(*)[168])(smem + 43008);      // 64*168*2 = 21504
    unsigned short (*qs)[80]   = (unsigned short(*)[80])(smem + 64512);       // 64*80*2  = 10240
    unsigned short (*ks)[72]   = (unsigned short(*)[72])(smem + 74752);       // 144*72*2 = 20736

    const int tid  = threadIdx.x;
    const int lane = tid & 63;
    const int w    = tid >> 6;
    const int l15  = lane & 15, hi = lane >> 4;
    const int t0 = blockIdx.x * 64;
    const int h  = blockIdx.y;
    const int b  = blockIdx.z;
    const int jbase = t0 - 12;

    // ---- QKV phase: 22 jobs = {q:4, k:9, v:9} 16-row strips, K=256 ----
    for (int job = w; job < 22; job += 8) {
        int mat, strip;
        if (job < 4)       { mat = 0; strip = job; }
        else if (job < 13) { mat = 1; strip = job - 4; }
        else               { mat = 2; strip = job - 13; }
        const float* W    = (mat == 0) ? Wq : (mat == 1) ? Wk : Wv;
        const float* bias = (mat == 0) ? bq : (mat == 1) ? bk : bv;
        int rowbase = (mat == 0) ? t0 : jbase;
        int arow = rowbase + strip * 16 + l15;
        int arowc = arow < 0 ? 0 : (arow > T_SEQ - 1 ? T_SEQ - 1 : arow);
        const float* Ap = x + ((size_t)(b * T_SEQ + arowc)) * D_MODEL;
        f32x4v acc[4] = {};
        #pragma unroll
        for (int kt = 0; kt < 8; ++kt) {
            int koff = kt * 32 + hi * 8;
            s16x8 af = pack8(*(const float4*)(Ap + koff), *(const float4*)(Ap + koff + 4));
            #pragma unroll
            for (int c = 0; c < 4; ++c) {
                const float* Bp = W + ((size_t)(h * 64 + c * 16 + l15)) * D_MODEL + koff;
                s16x8 bf = pack8(*(const float4*)Bp, *(const float4*)(Bp + 4));
                acc[c] = __builtin_amdgcn_mfma_f32_16x16x32_bf16(af, bf, acc[c], 0, 0, 0);
            }
        }
        #pragma unroll
        for (int c = 0; c < 4; ++c) {
            int col = c * 16 + l15;
            float bs = bias[h * 64 + col];
            #pragma unroll
            for (int r = 0; r < 4; ++r) {
                int rt = strip * 16 + hi * 4 + r;
                float val = acc[c][r] + bs;
                if (mat == 0) {
                    qs[rt][col] = f2bf(val);
                } else {
                    int j = jbase + rt;
                    unsigned short ov = (j >= 0 && j < T_SEQ) ? f2bf(val) : (unsigned short)0;
                    if (mat == 1) ks[rt][col] = ov;
                    else          v0T[col][rt] = ov;
                }
            }
        }
    }
    // zero v0T tail slots [144,168) so PV's 0 * garbage can't make NaN
    for (int i = tid; i < 64 * 24; i += 512) v0T[i / 24][144 + (i % 24)] = 0;
    __syncthreads();

    // ---- P1: S[qrow][slot] = q . k^T  (64 x 144, K=64) ----
    {
        int rs  = w & 3;
        int cf0 = (w < 4) ? 0 : 5;
        int ncf = (w < 4) ? 5 : 4;
        s16x8 aq0 = *(const s16x8*)&qs[rs * 16 + l15][hi * 8];
        s16x8 aq1 = *(const s16x8*)&qs[rs * 16 + l15][32 + hi * 8];
        for (int cf = cf0; cf < cf0 + ncf; ++cf) {
            s16x8 b0 = *(const s16x8*)&ks[cf * 16 + l15][hi * 8];
            s16x8 b1 = *(const s16x8*)&ks[cf * 16 + l15][32 + hi * 8];
            f32x4v acc = {};
            acc = __builtin_amdgcn_mfma_f32_16x16x32_bf16(aq0, b0, acc, 0, 0, 0);
            acc = __builtin_amdgcn_mfma_f32_16x16x32_bf16(aq1, b1, acc, 0, 0, 0);
            #pragma unroll
            for (int r = 0; r < 4; ++r)
                S[rs * 16 + hi * 4 + r][cf * 16 + l15] = acc[r];
        }
    }
    __syncthreads();

    // ---- Phase C: window softmax, 8 threads / query ----
    float l0 = shift_logits[h * 4 + 0], l1 = shift_logits[h * 4 + 1];
    float l2 = shift_logits[h * 4 + 2], l3 = shift_logits[h * 4 + 3];
    float mx = fmaxf(fmaxf(l0, l1), fmaxf(l2, l3));
    float s0 = __expf(l0 - mx), s1 = __expf(l1 - mx), s2 = __expf(l2 - mx), s3 = __expf(l3 - mx);
    float inv = 1.0f / (s0 + s1 + s2 + s3);
    float pi0 = s0 * inv + 1e-8f, pi1 = s1 * inv + 1e-8f;
    float pi2 = s2 * inv + 1e-8f, pi3 = s3 * inv + 1e-8f;
    float slope = alibi_slope[h];

    const int tq = tid >> 3;   // local query row
    const int g  = tid & 7;
    const int tg = t0 + tq;
    float att[8];
    #pragma unroll
    for (int u = 0; u < 8; ++u) {
        int o = g + 8 * u;
        int k = tg + o;
        if (k < T_SEQ) {
            int r0 = tq + o + 12;
            float z = pi0 * __expf(0.125f * S[tq][r0])
                    + pi1 * __expf(0.125f * S[tq][r0 - 4])
                    + pi2 * __expf(0.125f * S[tq][r0 - 8])
                    + pi3 * __expf(0.125f * S[tq][r0 - 12]);
            att[u] = __logf(z) - slope * (float)o;
        } else att[u] = -1e30f;
    }
    float m = att[0];
    #pragma unroll
    for (int u = 1; u < 8; ++u) m = fmaxf(m, att[u]);
    m = fmaxf(m, __shfl_xor(m, 1));
    m = fmaxf(m, __shfl_xor(m, 2));
    m = fmaxf(m, __shfl_xor(m, 4));
    float Zs = 0.0f;
    #pragma unroll
    for (int u = 0; u < 8; ++u) { att[u] = __expf(att[u] - m); Zs += att[u]; }
    Zs += __shfl_xor(Zs, 1);
    Zs += __shfl_xor(Zs, 2);
    Zs += __shfl_xor(Zs, 4);
    float rz = 1.0f / Zs;

    // write p into slot (k - jbase); zero-fill edges (same row, same wave -> lockstep-safe)
    #pragma unroll
    for (int u = 0; u < 8; ++u) S[tq][tq + g + 8 * u + 12] = att[u] * rz;
    for (int i = g; i < 24; i += 8) {
        int slot = tq + (i < 12 ? i : i + 64);
        S[tq][slot] = 0.0f;
    }
    // in-place P2: S[tq][rj] <- sum_s p[rj+4s]; ascending rj, reads stay ahead of writes
    for (int rj = g; rj < 164; rj += 8) {
        float val = 0.0f;
        if (rj >= tq && rj <= tq + 75)
            val = S[tq][rj] + S[tq][rj + 4] + S[tq][rj + 8] + S[tq][rj + 12];
        S[tq][rj] = val;
    }
    __syncthreads();

    // ---- PV: ctx = P2 @ v0T  (64 x 64, K=160) ----
    {
        int rs    = w & 3;
        int cbase = (w >> 2) * 2;
        s16x8 ap[5];
        #pragma unroll
        for (int kt = 0; kt < 5; ++kt) {
            const float* sp = &S[rs * 16 + l15][kt * 32 + hi * 8];
            ap[kt] = pack8(*(const float4*)sp, *(const float4*)(sp + 4));
        }
        f32x4v acc[2] = {};
        #pragma unroll
        for (int c = 0; c < 2; ++c) {
            #pragma unroll
            for (int kt = 0; kt < 5; ++kt) {
                s16x8 bv8 = *(const s16x8*)&v0T[(cbase + c) * 16 + l15][kt * 32 + hi * 8];
                acc[c] = __builtin_amdgcn_mfma_f32_16x16x32_bf16(ap[kt], bv8, acc[c], 0, 0, 0);
            }
        }
        #pragma unroll
        for (int c = 0; c < 2; ++c) {
            int d = (cbase + c) * 16 + l15;
            #pragma unroll
            for (int r = 0; r < 4; ++r) {
                int row = t0 + rs * 16 + hi * 4 + r;
                ctxb[((size_t)(b * T_SEQ + row)) * D_MODEL + h * 64 + d] = f2bf(acc[c][r]);
            }
        }
    }
}

// ---- O GEMM: out = ctx @ Wo^T + bo, Wo converted f32->bf16 on the fly ----
__global__ __launch_bounds__(256) void gemm_o_f32w(
    const unsigned short* __restrict__ ctxb, const float* __restrict__ Wo,
    const float* __restrict__ bo, float* __restrict__ out)
{
    const int lane = threadIdx.x & 63;
    const int w    = threadIdx.x >> 6;
    const int l15  = lane & 15, hi = lane >> 4;
    const int row0 = blockIdx.x * 64;
    const int col0 = blockIdx.y * 64;

    f32x4v acc[4] = {};
    const int arow = row0 + w * 16 + l15;
    #pragma unroll
    for (int kt = 0; kt < 8; ++kt) {
        int koff = kt * 32 + hi * 8;
        s16x8 a = *(const s16x8*)(ctxb + (size_t)arow * D_MODEL + koff);
        #pragma unroll
        for (int c = 0; c < 4; ++c) {
            const float* Bp = Wo + (size_t)(col0 + c * 16 + l15) * D_MODEL + koff;
            s16x8 bf = pack8(*(const float4*)Bp, *(const float4*)(Bp + 4));
            acc[c] = __builtin_amdgcn_mfma_f32_16x16x32_bf16(a, bf, acc[c], 0, 0, 0);
        }
    }
    #pragma unroll
    for (int c = 0; c < 4; ++c) {
        int col = col0 + c * 16 + l15;
        float bs = bo[col];
        #pragma unroll
        for (int r = 0; r < 4; ++r) {
            int row = row0 + w * 16 + hi * 4 + r;
            out[(size_t)row * D_MODEL + col] = acc[c][r] + bs;
        }
    }
}

extern "C" void kernel_launch(void* const* d_in, const int* in_sizes, int n_in,
                              void* d_out, int out_size, void* d_ws, size_t ws_size,
                              hipStream_t stream) {
    const float* x  = (const float*)d_in[0];
    const float* Wq = (const float*)d_in[1];
    const float* bq = (const float*)d_in[2];
    const float* Wk = (const float*)d_in[3];
    const float* bk = (const float*)d_in[4];
    const float* Wv = (const float*)d_in[5];
    const float* bv = (const float*)d_in[6];
    const float* Wo = (const float*)d_in[7];
    const float* bo = (const float*)d_in[8];
    const float* shift_logits = (const float*)d_in[9];
    const float* alibi_slope  = (const float*)d_in[10];
    float* out = (float*)d_out;

    unsigned short* ctx = (unsigned short*)d_ws;   // 4096 x 256 bf16 = 2 MB

    hipFuncSetAttribute(reinterpret_cast<const void*>(attn_fused),
                        hipFuncAttributeMaxDynamicSharedMemorySize, SMEM_BYTES);

    attn_fused<<<dim3(16, 4, 4), dim3(512), SMEM_BYTES, stream>>>(
        x, Wq, bq, Wk, bk, Wv, bv, shift_logits, alibi_slope, ctx);
    gemm_o_f32w<<<dim3(64, 4), dim3(256), 0, stream>>>(ctx, Wo, bo, out);
}

// Round 3
// 33.455 us; speedup vs baseline: 2.1697x; 2.1697x over previous
//
#include <hip/hip_runtime.h>
#include <hip/hip_bf16.h>

#define T_SEQ 1024
#define D_MODEL 256
#define QBLK 32
#define NS 112     // staged k/v rows per tile: j in [t0-12, t0+100)
#define KPV 128    // PV K extent (4 x 32)

typedef __attribute__((ext_vector_type(8))) short s16x8;
typedef __attribute__((ext_vector_type(4))) float f32x4v;

__device__ __forceinline__ unsigned short f2bf(float x) {
    union { float f; unsigned int u; } v; v.f = x;
    unsigned int r = v.u + 0x7FFFu + ((v.u >> 16) & 1u);
    return (unsigned short)(r >> 16);
}

// 8 consecutive f32 -> bf16x8 (v_cvt_pk_bf16_f32 pairs)
__device__ __forceinline__ s16x8 pack8(float4 a, float4 b) {
    union { s16x8 v; unsigned int u[4]; } r;
    union { __hip_bfloat162 h; unsigned int u; } t;
    t.h = __float22bfloat162_rn(make_float2(a.x, a.y)); r.u[0] = t.u;
    t.h = __float22bfloat162_rn(make_float2(a.z, a.w)); r.u[1] = t.u;
    t.h = __float22bfloat162_rn(make_float2(b.x, b.y)); r.u[2] = t.u;
    t.h = __float22bfloat162_rn(make_float2(b.z, b.w)); r.u[3] = t.u;
    return r.v;
}

// ---- QKV GEMM: Y = scale*(x @ W^T + b) -> bf16. W staged f32->bf16 in LDS. ----
// grid (64, 12): by>>2 = mat (q/k/v), (by&3)*64 = col tile. 64x64 tile, 4 waves.
__global__ __launch_bounds__(256) void qkv_gemm(
    const float* __restrict__ x,
    const float* __restrict__ Wq, const float* __restrict__ bq,
    const float* __restrict__ Wk, const float* __restrict__ bk,
    const float* __restrict__ Wv, const float* __restrict__ bv,
    unsigned short* __restrict__ qb, unsigned short* __restrict__ kb,
    unsigned short* __restrict__ vb)
{
    __shared__ unsigned short Bl[64][264];   // 33792 B, stride 528 B (16-mult, conflict-benign)

    const int tid  = threadIdx.x;
    const int lane = tid & 63;
    const int w    = tid >> 6;
    const int l15  = lane & 15, hi = lane >> 4;
    const int row0 = blockIdx.x * 64;
    const int mat  = blockIdx.y >> 2;
    const int col0 = (blockIdx.y & 3) * 64;

    const float* W    = (mat == 0) ? Wq : (mat == 1) ? Wk : Wv;
    const float* bias = (mat == 0) ? bq : (mat == 1) ? bk : bv;
    unsigned short* out = (mat == 0) ? qb : (mat == 1) ? kb : vb;
    const float scale = (mat == 0) ? 0.125f : 1.0f;   // 1/sqrt(DH) folded into q

    // stage W tile: 64 rows x 256 cols f32 -> bf16, coalesced float4 loads
    for (int i = tid; i < 2048; i += 256) {
        int r = i >> 5, c8 = i & 31;
        const float* p = W + (size_t)(col0 + r) * D_MODEL + c8 * 8;
        *(s16x8*)&Bl[r][c8 * 8] = pack8(*(const float4*)p, *(const float4*)(p + 4));
    }
    __syncthreads();

    const int arow = row0 + w * 16 + l15;
    const float* Ap = x + (size_t)arow * D_MODEL;
    f32x4v acc[4] = {};
    #pragma unroll
    for (int kt = 0; kt < 8; ++kt) {
        int koff = kt * 32 + hi * 8;
        s16x8 a = pack8(*(const float4*)(Ap + koff), *(const float4*)(Ap + koff + 4));
        #pragma unroll
        for (int c = 0; c < 4; ++c)
            acc[c] = __builtin_amdgcn_mfma_f32_16x16x32_bf16(a, *(const s16x8*)&Bl[c * 16 + l15][koff], acc[c], 0, 0, 0);
    }
    #pragma unroll
    for (int c = 0; c < 4; ++c) {
        int col = col0 + c * 16 + l15;
        float bs = bias[col];
        #pragma unroll
        for (int r = 0; r < 4; ++r) {
            int row = row0 + w * 16 + hi * 4 + r;
            out[(size_t)row * D_MODEL + col] = f2bf((acc[c][r] + bs) * scale);
        }
    }
}

// ---- attention: 32-query tiles, 512 threads, 50.4 KB static LDS (2 blocks/CU) ----
__global__ __launch_bounds__(512) void attn32(
    const unsigned short* __restrict__ qb, const unsigned short* __restrict__ kb,
    const unsigned short* __restrict__ vb,
    const float* __restrict__ shift_logits, const float* __restrict__ alibi_slope,
    unsigned short* __restrict__ ctxb)
{
    __shared__ float S[QBLK][132];           // 16896 B, stride 528 B
    __shared__ unsigned short ks[NS][72];    // 16128 B, stride 144 B
    __shared__ unsigned short v0T[64][136];  // 17408 B, stride 272 B

    const int tid  = threadIdx.x;
    const int lane = tid & 63;
    const int w    = tid >> 6;
    const int l15  = lane & 15, hi = lane >> 4;
    const int t0 = blockIdx.x * QBLK;
    const int h  = blockIdx.y;
    const int b  = blockIdx.z;
    const int jbase = t0 - 12;

    // stage ks[rt][d] = k[b, jbase+rt, h*64+d], zero OOB rows
    for (int task = tid; task < NS * 8; task += 512) {
        int rt = task >> 3, c8 = task & 7;
        int j = jbase + rt;
        s16x8 kv = {0, 0, 0, 0, 0, 0, 0, 0};
        if (j >= 0 && j < T_SEQ)
            kv = *(const s16x8*)(kb + ((size_t)(b * T_SEQ + j)) * D_MODEL + h * 64 + c8 * 8);
        *(s16x8*)&ks[rt][c8 * 8] = kv;
    }
    // stage v0T[d][rt] (transposed), zero OOB
    for (int task = tid; task < NS * 8; task += 512) {
        int rt = task >> 3, c8 = task & 7;
        int j = jbase + rt;
        s16x8 vv = {0, 0, 0, 0, 0, 0, 0, 0};
        if (j >= 0 && j < T_SEQ)
            vv = *(const s16x8*)(vb + ((size_t)(b * T_SEQ + j)) * D_MODEL + h * 64 + c8 * 8);
        #pragma unroll
        for (int e = 0; e < 8; ++e) v0T[c8 * 8 + e][rt] = (unsigned short)vv[e];
    }
    // zero v0T tail cols [NS, 136) so PV's 0*garbage can't NaN
    for (int i = tid; i < 64 * 24; i += 512) v0T[i / 24][NS + (i % 24)] = 0;
    __syncthreads();

    // P1: S[q][slot] = q . k^T  (32 x 112, K=64). 14 units = strip(2) x cf(7).
    for (int u = w; u < 14; u += 8) {
        int rs = u & 1, cf = u >> 1;
        const unsigned short* qrow = qb + ((size_t)(b * T_SEQ + t0 + rs * 16 + l15)) * D_MODEL + h * 64;
        s16x8 aq0 = *(const s16x8*)(qrow + hi * 8);
        s16x8 aq1 = *(const s16x8*)(qrow + 32 + hi * 8);
        s16x8 b0 = *(const s16x8*)&ks[cf * 16 + l15][hi * 8];
        s16x8 b1 = *(const s16x8*)&ks[cf * 16 + l15][32 + hi * 8];
        f32x4v acc = {};
        acc = __builtin_amdgcn_mfma_f32_16x16x32_bf16(aq0, b0, acc, 0, 0, 0);
        acc = __builtin_amdgcn_mfma_f32_16x16x32_bf16(aq1, b1, acc, 0, 0, 0);
        #pragma unroll
        for (int r = 0; r < 4; ++r)
            S[rs * 16 + hi * 4 + r][cf * 16 + l15] = acc[r];
    }
    __syncthreads();

    // window softmax over the 4 shifts; 16 threads per query
    float l0 = shift_logits[h * 4 + 0], l1 = shift_logits[h * 4 + 1];
    float l2 = shift_logits[h * 4 + 2], l3 = shift_logits[h * 4 + 3];
    float mx = fmaxf(fmaxf(l0, l1), fmaxf(l2, l3));
    float s0 = __expf(l0 - mx), s1 = __expf(l1 - mx), s2 = __expf(l2 - mx), s3 = __expf(l3 - mx);
    float inv = 1.0f / (s0 + s1 + s2 + s3);
    float pi0 = s0 * inv + 1e-8f, pi1 = s1 * inv + 1e-8f;
    float pi2 = s2 * inv + 1e-8f, pi3 = s3 * inv + 1e-8f;
    float slope = alibi_slope[h];

    const int tq = tid >> 4;     // local query row (32 per block)
    const int g  = tid & 15;
    const int tg = t0 + tq;
    float att[4];
    #pragma unroll
    for (int u = 0; u < 4; ++u) {
        int o = g + 16 * u;
        int k = tg + o;
        if (k < T_SEQ) {
            int r0 = tq + o + 12;
            float z = pi0 * __expf(S[tq][r0])     + pi1 * __expf(S[tq][r0 - 4])
                    + pi2 * __expf(S[tq][r0 - 8]) + pi3 * __expf(S[tq][r0 - 12]);
            att[u] = __logf(z) - slope * (float)o;
        } else att[u] = -1e30f;
    }
    float m = att[0];
    #pragma unroll
    for (int u = 1; u < 4; ++u) m = fmaxf(m, att[u]);
    m = fmaxf(m, __shfl_xor(m, 1));
    m = fmaxf(m, __shfl_xor(m, 2));
    m = fmaxf(m, __shfl_xor(m, 4));
    m = fmaxf(m, __shfl_xor(m, 8));
    float Zs = 0.0f;
    #pragma unroll
    for (int u = 0; u < 4; ++u) { att[u] = __expf(att[u] - m); Zs += att[u]; }
    Zs += __shfl_xor(Zs, 1);
    Zs += __shfl_xor(Zs, 2);
    Zs += __shfl_xor(Zs, 4);
    Zs += __shfl_xor(Zs, 8);
    float rz = 1.0f / Zs;

    // p into slot (k - jbase); zero edges [tq,tq+11] and [tq+76,tq+87]
    // (all 16 writers of a row are in one wave -> lockstep-safe with the reads above)
    #pragma unroll
    for (int u = 0; u < 4; ++u) S[tq][tq + g + 16 * u + 12] = att[u] * rz;
    for (int i = g; i < 24; i += 16) {
        int slot = tq + (i < 12 ? i : i + 64);
        S[tq][slot] = 0.0f;
    }
    // in-place P2: S[tq][rj] <- sum_{s} p[rj+4s]; ascending rj, reads stay ahead of writes
    for (int rj = g; rj < KPV; rj += 16) {
        float val = 0.0f;
        if (rj >= tq && rj <= tq + 75)
            val = S[tq][rj] + S[tq][rj + 4] + S[tq][rj + 8] + S[tq][rj + 12];
        S[tq][rj] = val;
    }
    __syncthreads();

    // PV: ctx = P2 @ v0T (32 x 64, K=128). 8 units = strip(2) x colfrag(4), one per wave.
    {
        int rs = w & 1, c = w >> 1;
        s16x8 ap[4];
        #pragma unroll
        for (int kt = 0; kt < 4; ++kt) {
            const float* sp = &S[rs * 16 + l15][kt * 32 + hi * 8];
            ap[kt] = pack8(*(const float4*)sp, *(const float4*)(sp + 4));
        }
        f32x4v acc = {};
        #pragma unroll
        for (int kt = 0; kt < 4; ++kt)
            acc = __builtin_amdgcn_mfma_f32_16x16x32_bf16(ap[kt], *(const s16x8*)&v0T[c * 16 + l15][kt * 32 + hi * 8], acc, 0, 0, 0);
        #pragma unroll
        for (int r = 0; r < 4; ++r) {
            int row = t0 + rs * 16 + hi * 4 + r;
            ctxb[((size_t)(b * T_SEQ + row)) * D_MODEL + h * 64 + c * 16 + l15] = f2bf(acc[r]);
        }
    }
}

// ---- O GEMM: out = ctx @ Wo^T + bo (f32 out). Wo staged f32->bf16 in LDS. ----
__global__ __launch_bounds__(256) void gemm_o(
    const unsigned short* __restrict__ ctxb, const float* __restrict__ Wo,
    const float* __restrict__ bo, float* __restrict__ out)
{
    __shared__ unsigned short Bl[64][264];

    const int tid  = threadIdx.x;
    const int lane = tid & 63;
    const int w    = tid >> 6;
    const int l15  = lane & 15, hi = lane >> 4;
    const int row0 = blockIdx.x * 64;
    const int col0 = blockIdx.y * 64;

    for (int i = tid; i < 2048; i += 256) {
        int r = i >> 5, c8 = i & 31;
        const float* p = Wo + (size_t)(col0 + r) * D_MODEL + c8 * 8;
        *(s16x8*)&Bl[r][c8 * 8] = pack8(*(const float4*)p, *(const float4*)(p + 4));
    }
    __syncthreads();

    const int arow = row0 + w * 16 + l15;
    f32x4v acc[4] = {};
    #pragma unroll
    for (int kt = 0; kt < 8; ++kt) {
        int koff = kt * 32 + hi * 8;
        s16x8 a = *(const s16x8*)(ctxb + (size_t)arow * D_MODEL + koff);
        #pragma unroll
        for (int c = 0; c < 4; ++c)
            acc[c] = __builtin_amdgcn_mfma_f32_16x16x32_bf16(a, *(const s16x8*)&Bl[c * 16 + l15][koff], acc[c], 0, 0, 0);
    }
    #pragma unroll
    for (int c = 0; c < 4; ++c) {
        int col = col0 + c * 16 + l15;
        float bs = bo[col];
        #pragma unroll
        for (int r = 0; r < 4; ++r) {
            int row = row0 + w * 16 + hi * 4 + r;
            out[(size_t)row * D_MODEL + col] = acc[c][r] + bs;
        }
    }
}

extern "C" void kernel_launch(void* const* d_in, const int* in_sizes, int n_in,
                              void* d_out, int out_size, void* d_ws, size_t ws_size,
                              hipStream_t stream) {
    const float* x  = (const float*)d_in[0];
    const float* Wq = (const float*)d_in[1];
    const float* bq = (const float*)d_in[2];
    const float* Wk = (const float*)d_in[3];
    const float* bk = (const float*)d_in[4];
    const float* Wv = (const float*)d_in[5];
    const float* bv = (const float*)d_in[6];
    const float* Wo = (const float*)d_in[7];
    const float* bo = (const float*)d_in[8];
    const float* shift_logits = (const float*)d_in[9];
    const float* alibi_slope  = (const float*)d_in[10];
    float* out = (float*)d_out;

    unsigned short* qb  = (unsigned short*)d_ws;          // 4096x256 bf16 = 2 MB
    unsigned short* kb  = qb + (1u << 20);
    unsigned short* vb  = kb + (1u << 20);
    unsigned short* ctx = vb + (1u << 20);

    qkv_gemm<<<dim3(64, 12), dim3(256), 0, stream>>>(x, Wq, bq, Wk, bk, Wv, bv, qb, kb, vb);
    attn32<<<dim3(T_SEQ / QBLK, 4, 4), dim3(512), 0, stream>>>(qb, kb, vb, shift_logits, alibi_slope, ctx);
    gemm_o<<<dim3(64, 4), dim3(256), 0, stream>>>(ctx, Wo, bo, out);
}